// Round 4
// baseline (412.702 us; speedup 1.0000x reference)
//
#include <hip/hip_runtime.h>
#include <math.h>

// BS=128, L=256, D=512, H=2, DK=256.
// Conv branches dead (gather idx < 256). Split-bf16 (hi/lo) MFMA GEMMs.
// Algebraic eliminations: A = Fq(Q(x)) via composed weight Wa = Wfq@Wq_h
// (Q only materialized at the 128 gathered rows, fp32); V GEMM removed via
// x = (p@cap)@Wv^T + bv. Score partials fused into kg GEMM epilogue.

typedef short bf16x8 __attribute__((ext_vector_type(8)));
typedef float f32x4 __attribute__((ext_vector_type(4)));
typedef short short4v __attribute__((ext_vector_type(4)));

__device__ __forceinline__ short f2bf(float x) {
    union { float f; unsigned u; } c; c.f = x;
    unsigned r = c.u + 0x7FFFu + ((c.u >> 16) & 1u);
    return (short)(r >> 16);
}
__device__ __forceinline__ float bf2f(short h) {
    union { float f; unsigned u; } c; c.u = ((unsigned)(unsigned short)h) << 16;
    return c.f;
}
__device__ __forceinline__ void glds16(const void* g, void* l) {
    __builtin_amdgcn_global_load_lds(
        (const __attribute__((address_space(1))) void*)g,
        (__attribute__((address_space(3))) void*)l, 16, 0, 0);
}

// ---------------- split fp32 -> bf16 hi/lo ----------------
struct SplitArgs {
    const float* src[4];
    short* hi[4];
    short* lo[4];
    int n4[4];
};
__global__ __launch_bounds__(256) void split_multi(SplitArgs a)
{
    const int j = blockIdx.y;
    const float4* s = (const float4*)a.src[j];
    short* hi = a.hi[j];
    short* lo = a.lo[j];
    const int n4 = a.n4[j];
    for (int i = blockIdx.x * 256 + threadIdx.x; i < n4; i += gridDim.x * 256) {
        float4 x = s[i];
        short4v h, l;
        h.x = f2bf(x.x); l.x = f2bf(x.x - bf2f(h.x));
        h.y = f2bf(x.y); l.y = f2bf(x.y - bf2f(h.y));
        h.z = f2bf(x.z); l.z = f2bf(x.z - bf2f(h.z));
        h.w = f2bf(x.w); l.w = f2bf(x.w - bf2f(h.w));
        *(short4v*)&hi[i * 4] = h;
        *(short4v*)&lo[i * 4] = l;
    }
}

// ---------------- composed weight Wa = Wfq @ Wq_h, ba = Wfq@bq_h + bfq ----------------
__global__ __launch_bounds__(256)
void compose(const float* __restrict__ Wq, const float* __restrict__ bq,
             const float* __restrict__ Wfq, const float* __restrict__ bfq,
             short* __restrict__ WBhi, short* __restrict__ WBlo, float* __restrict__ ba)
{
    __shared__ float fq[256];
    __shared__ float redc[256];
    const int op = blockIdx.x;          // 0..511: h = op>>8, o = op&255
    const int h = op >> 8, o = op & 255;
    const int t = threadIdx.x;
    fq[t] = Wfq[o * 256 + t];
    redc[t] = fq[t] * bq[h * 256 + t];
    __syncthreads();
    for (int s = 128; s > 0; s >>= 1) {
        if (t < s) redc[t] += redc[t + s];
        __syncthreads();
    }
    if (t == 0) ba[op] = redc[0] + bfq[o];
    float s0 = 0.f, s1 = 0.f;
    for (int d = 0; d < 256; ++d) {
        const float f = fq[d];
        const float* wr = Wq + (size_t)(h * 256 + d) * 512;
        s0 += f * wr[t];
        s1 += f * wr[t + 256];
    }
    const size_t ro = (size_t)(512 + op) * 512;
    short h0 = f2bf(s0);
    WBhi[ro + t] = h0; WBlo[ro + t] = f2bf(s0 - bf2f(h0));
    short h1 = f2bf(s1);
    WBhi[ro + 256 + t] = h1; WBlo[ro + 256 + t] = f2bf(s1 - bf2f(h1));
}

// ---------------- chunked split K-loop, 2-phase double buffered ----------------
__device__ __forceinline__ void run_kloop(
    const short* __restrict__ Ahi, const short* __restrict__ Alo, int lda,
    const short* __restrict__ Bhi, const short* __restrict__ Blo, int ldb,
    int K, int bm, int bn, short (*lds)[16384], int tid, f32x4 acc[4][4])
{
    const int lane = tid & 63;
    const int wr = (tid >> 7) & 1;
    const int wc = (tid >> 6) & 1;
    const int fr = lane & 15, kc = lane >> 4;
    const int r0 = tid >> 2;
    const int e0 = (tid & 3) * 8;
    const int NS = K / 32;

    auto stage = [&](int ph, int k0) {
        short* b = lds[ph];
        glds16(Ahi + (size_t)(bm + r0) * lda + k0 + e0,      b + tid * 8);
        glds16(Ahi + (size_t)(bm + r0 + 64) * lda + k0 + e0, b + (tid + 256) * 8);
        glds16(Bhi + (size_t)(bn + r0) * ldb + k0 + e0,      b + 4096 + tid * 8);
        glds16(Bhi + (size_t)(bn + r0 + 64) * ldb + k0 + e0, b + 4096 + (tid + 256) * 8);
        glds16(Alo + (size_t)(bm + r0) * lda + k0 + e0,      b + 8192 + tid * 8);
        glds16(Alo + (size_t)(bm + r0 + 64) * lda + k0 + e0, b + 8192 + (tid + 256) * 8);
        glds16(Blo + (size_t)(bn + r0) * ldb + k0 + e0,      b + 12288 + tid * 8);
        glds16(Blo + (size_t)(bn + r0 + 64) * ldb + k0 + e0, b + 12288 + (tid + 256) * 8);
    };

    stage(0, 0);
    __syncthreads();
    for (int s = 0; s < NS; ++s) {
        if (s + 1 < NS) stage((s + 1) & 1, (s + 1) * 32);
        const short* b = lds[s & 1];
        bf16x8 ah[4], bh[4];
#pragma unroll
        for (int i = 0; i < 4; ++i)
            ah[i] = *(const bf16x8*)&b[(wr * 64 + i * 16 + fr) * 32 + kc * 8];
#pragma unroll
        for (int i = 0; i < 4; ++i)
            bh[i] = *(const bf16x8*)&b[4096 + (wc * 64 + i * 16 + fr) * 32 + kc * 8];
#pragma unroll
        for (int mi = 0; mi < 4; ++mi)
#pragma unroll
            for (int ni = 0; ni < 4; ++ni)
                acc[mi][ni] = __builtin_amdgcn_mfma_f32_16x16x32_bf16(ah[mi], bh[ni], acc[mi][ni], 0, 0, 0);
        bf16x8 al[4], bl[4];
#pragma unroll
        for (int i = 0; i < 4; ++i)
            al[i] = *(const bf16x8*)&b[8192 + (wr * 64 + i * 16 + fr) * 32 + kc * 8];
#pragma unroll
        for (int mi = 0; mi < 4; ++mi)
#pragma unroll
            for (int ni = 0; ni < 4; ++ni)
                acc[mi][ni] = __builtin_amdgcn_mfma_f32_16x16x32_bf16(al[mi], bh[ni], acc[mi][ni], 0, 0, 0);
#pragma unroll
        for (int i = 0; i < 4; ++i)
            bl[i] = *(const bf16x8*)&b[12288 + (wc * 64 + i * 16 + fr) * 32 + kc * 8];
#pragma unroll
        for (int mi = 0; mi < 4; ++mi)
#pragma unroll
            for (int ni = 0; ni < 4; ++ni)
                acc[mi][ni] = __builtin_amdgcn_mfma_f32_16x16x32_bf16(ah[mi], bl[ni], acc[mi][ni], 0, 0, 0);
        __syncthreads();
    }
}

// MODE 1: KA — split-write (acc + bias[col<512? bk : ba[col-512]]), ldc 1024
// MODE 3: FkG — split-write of (acc+bias)*(E1+E2)
// MODE 4: kg+score — no write; partial score rows into scorep
template<int MODE>
__global__ __launch_bounds__(256, 2)
void gemm_mfma(const short* __restrict__ Ahi, const short* __restrict__ Alo,
               int lda, int aoff,
               const short* __restrict__ Bhi, const short* __restrict__ Blo, int ldb,
               const float* __restrict__ bias, const float* __restrict__ bias2,
               const short* __restrict__ E1, const short* __restrict__ E2, int ldep, int eoff,
               const float* __restrict__ qg, float* __restrict__ scorep,
               short* __restrict__ C0, short* __restrict__ C1, int ldc, int coff,
               int K)
{
    __shared__ short lds[2][16384];
    __shared__ float sp[256];
    const int tid = threadIdx.x;
    const int bm = blockIdx.y * 128;
    const int bn = blockIdx.x * 128;
    const int z = blockIdx.z;

    f32x4 acc[4][4];
#pragma unroll
    for (int i = 0; i < 4; ++i)
#pragma unroll
        for (int j = 0; j < 4; ++j) acc[i][j] = (f32x4){0.f, 0.f, 0.f, 0.f};
    run_kloop(Ahi + (size_t)z * aoff, Alo + (size_t)z * aoff, lda,
              Bhi, Blo, ldb, K, bm, bn, lds, tid, acc);

    const int lane = tid & 63;
    const int wr = (tid >> 7) & 1, wc = (tid >> 6) & 1;
    const int fr = lane & 15, kc = lane >> 4;

    float qgv[4];
    float pt[4][4];
    if (MODE == 4) {
        const int b = bm >> 8;
#pragma unroll
        for (int ni = 0; ni < 4; ++ni)
            qgv[ni] = qg[b * 512 + z * 256 + bn + wc * 64 + ni * 16 + fr];
#pragma unroll
        for (int mi = 0; mi < 4; ++mi)
#pragma unroll
            for (int r = 0; r < 4; ++r) pt[mi][r] = 0.f;
    }

#pragma unroll
    for (int mi = 0; mi < 4; ++mi) {
#pragma unroll
        for (int ni = 0; ni < 4; ++ni) {
#pragma unroll
            for (int r = 0; r < 4; ++r) {
                const int row = bm + wr * 64 + mi * 16 + kc * 4 + r;
                const int col = bn + wc * 64 + ni * 16 + fr;
                float bb = (MODE == 1) ? (col < 512 ? bias[col] : bias2[col - 512]) : bias[col];
                float v = acc[mi][ni][r] + bb;
                if (MODE == 1) {
                    const size_t off = (size_t)row * ldc + col;
                    short h = f2bf(v);
                    C0[off] = h;
                    C1[off] = f2bf(v - bf2f(h));
                } else if (MODE == 3) {
                    const size_t eoffs = (size_t)row * ldep + z * eoff + col;
                    float e = bf2f(E1[eoffs]) + bf2f(E2[eoffs]);
                    float p = v * e;
                    const size_t off = (size_t)row * ldc + z * coff + col;
                    short h = f2bf(p);
                    C0[off] = h;
                    C1[off] = f2bf(p - bf2f(h));
                } else if (MODE == 4) {
                    const size_t eoffs = (size_t)row * ldep + z * eoff + col;
                    float e = bf2f(E1[eoffs]) + bf2f(E2[eoffs]);
                    float kgv = e / (1.f + expf(-v));
                    pt[mi][r] += kgv * qgv[ni];
                }
            }
        }
    }

    if (MODE == 4) {
#pragma unroll
        for (int mi = 0; mi < 4; ++mi) {
#pragma unroll
            for (int r = 0; r < 4; ++r) {
                float p = pt[mi][r];
                p += __shfl_xor(p, 1);
                p += __shfl_xor(p, 2);
                p += __shfl_xor(p, 4);
                p += __shfl_xor(p, 8);
                if (fr == 0) {
                    const int row_local = wr * 64 + mi * 16 + kc * 4 + r;
                    sp[row_local * 2 + wc] = p;
                }
            }
        }
        __syncthreads();
        if (tid < 128) {
            const int row = bm + tid;
            const float s = sp[tid * 2] + sp[tid * 2 + 1];
            const int b = row >> 8, j = row & 255;
            scorep[((size_t)(b * 2 + z) * 256 + j) * 2 + blockIdx.x] = s;
        }
    }
}

// ---------------- qg at gathered rows: Q fp32-exact from cap ----------------
__global__ __launch_bounds__(256)
void qg_kernel(const float* __restrict__ cap,
               const short* __restrict__ Ghi, const short* __restrict__ Glo,
               const float* __restrict__ Wq, const float* __restrict__ bq,
               const float* __restrict__ Wfg, const float* __restrict__ bfg,
               const int* __restrict__ lengths, float* __restrict__ qg)
{
    __shared__ float cr[512];
    __shared__ float gs[256];
    const int b = blockIdx.x >> 1, h = blockIdx.x & 1;
    const int t = threadIdx.x;
    int r = lengths[b] - 1;
    if (r < 0) r = 0;
    if (r > 255) r = 255;
    const size_t base = ((size_t)b * 256 + r) * 512;
    cr[t] = cap[base + t];
    cr[t + 256] = cap[base + 256 + t];
    gs[t] = bf2f(Ghi[base + h * 256 + t]) + bf2f(Glo[base + h * 256 + t]);
    __syncthreads();
    // Q[row, h*256+t] fp32
    const float4* wq4 = (const float4*)(Wq + (size_t)(h * 256 + t) * 512);
    float q = 0.f;
    for (int k4 = 0; k4 < 128; ++k4) {
        float4 w = wq4[k4];
        q += w.x * cr[k4 * 4 + 0] + w.y * cr[k4 * 4 + 1]
           + w.z * cr[k4 * 4 + 2] + w.w * cr[k4 * 4 + 3];
    }
    q += bq[h * 256 + t];
    // gate = sigmoid(Wfg[t,:] @ G_head + bfg[t])
    const float4* w4 = (const float4*)(Wfg + (size_t)t * 256);
    float a = 0.f;
    for (int k4 = 0; k4 < 64; ++k4) {
        float4 w = w4[k4];
        a += w.x * gs[k4 * 4 + 0] + w.y * gs[k4 * 4 + 1]
           + w.z * gs[k4 * 4 + 2] + w.w * gs[k4 * 4 + 3];
    }
    a += bfg[t];
    qg[b * 512 + h * 256 + t] = q / (1.f + expf(-a));
}

// ---------------- per-sample softmax + (p@cap)@Wv^T + BN1 + residual ----------------
__global__ __launch_bounds__(256)
void attn_tail(const float* __restrict__ scorep, const float* __restrict__ cap,
               const int* __restrict__ lengths,
               const float* __restrict__ Wv, const float* __restrict__ bv,
               const float* __restrict__ g1, const float* __restrict__ b1,
               const float* __restrict__ m1, const float* __restrict__ v1,
               float* __restrict__ xga)
{
    __shared__ float sc[512], red[512], pb[1024];
    const int b = blockIdx.x;
    const int t = threadIdx.x;
    int r = lengths[b] - 1;
    if (r < 0) r = 0;
    if (r > 255) r = 255;
    const size_t base = ((size_t)b * 256 + r) * 512;

#pragma unroll
    for (int i = 0; i < 2; ++i) {
        const int o = t + i * 256;
        const int h = o >> 8, j = o & 255;
        const size_t si = ((size_t)(b * 2 + h) * 256 + j) * 2;
        sc[o] = floorf((scorep[si] + scorep[si + 1]) * 0.0625f);
    }
    __syncthreads();

    red[t] = sc[t]; red[t + 256] = sc[t + 256];
    __syncthreads();
    for (int s = 128; s > 0; s >>= 1) {
        if (t < s) {
            red[t] = fmaxf(red[t], red[t + s]);
            red[256 + t] = fmaxf(red[256 + t], red[256 + t + s]);
        }
        __syncthreads();
    }
    const float mx0 = red[0], mx1 = red[256];
    __syncthreads();
    const float e0 = expf(sc[t] - mx0);
    const float e1 = expf(sc[t + 256] - mx1);
    red[t] = e0; red[t + 256] = e1;
    __syncthreads();
    for (int s = 128; s > 0; s >>= 1) {
        if (t < s) { red[t] += red[t + s]; red[256 + t] += red[256 + t + s]; }
        __syncthreads();
    }
    sc[t] = e0 / red[0];
    sc[t + 256] = e1 / red[256];
    __syncthreads();

    // pbar_h[i] = sum_j p_h[j] * cap[b,j,i]
    float a00 = 0.f, a01 = 0.f, a10 = 0.f, a11 = 0.f;
    for (int j = 0; j < 256; ++j) {
        const float p0 = sc[j], p1 = sc[256 + j];
        const float* cj = cap + ((size_t)(b * 256 + j)) * 512;
        const float c0v = cj[t];
        const float c1v = cj[t + 256];
        a00 += p0 * c0v; a01 += p0 * c1v;
        a10 += p1 * c0v; a11 += p1 * c1v;
    }
    pb[t] = a00; pb[256 + t] = a01;
    pb[512 + t] = a10; pb[768 + t] = a11;
    __syncthreads();

    // x[d'] = pbar_h . Wv[d',:] + bv[d'],  h = d'>>8
    float x0 = 0.f, x1 = 0.f;
    {
        const float4* w4 = (const float4*)(Wv + (size_t)t * 512);
        for (int k4 = 0; k4 < 128; ++k4) {
            float4 w = w4[k4];
            x0 += w.x * pb[k4 * 4 + 0] + w.y * pb[k4 * 4 + 1]
                + w.z * pb[k4 * 4 + 2] + w.w * pb[k4 * 4 + 3];
        }
        x0 += bv[t];
    }
    {
        const float4* w4 = (const float4*)(Wv + (size_t)(t + 256) * 512);
        for (int k4 = 0; k4 < 128; ++k4) {
            float4 w = w4[k4];
            x1 += w.x * pb[512 + k4 * 4 + 0] + w.y * pb[512 + k4 * 4 + 1]
                + w.z * pb[512 + k4 * 4 + 2] + w.w * pb[512 + k4 * 4 + 3];
        }
        x1 += bv[t + 256];
    }
    const int c0 = t, c1 = t + 256;
    const float s0 = g1[c0] / sqrtf(v1[c0] + 1e-5f);
    const float s1 = g1[c1] / sqrtf(v1[c1] + 1e-5f);
    xga[b * 512 + c0] = cap[base + c0] + (x0 - m1[c0]) * s0 + b1[c0];
    xga[b * 512 + c1] = cap[base + c1] + (x1 - m1[c1]) * s1 + b1[c1];
}

// ---------------- MLP strip GEMMs (weights read once) ----------------
__global__ __launch_bounds__(256)
void mlp1(const float* __restrict__ xga, const float* __restrict__ W,
          const float* __restrict__ bias, float* __restrict__ hid)
{
    __shared__ float xs[16 * 512];
    const int r0 = blockIdx.y * 16;
    const int c0 = blockIdx.x * 64;
    for (int i = threadIdx.x; i < 2048; i += 256)
        ((float4*)xs)[i] = ((const float4*)(xga + (size_t)r0 * 512))[i];
    __syncthreads();
    const int col = c0 + (threadIdx.x & 63);
    const int rg = (threadIdx.x >> 6) * 4;
    float acc[4] = {0.f, 0.f, 0.f, 0.f};
    const float4* w4 = (const float4*)(W + (size_t)col * 512);
    for (int k4 = 0; k4 < 128; ++k4) {
        float4 w = w4[k4];
#pragma unroll
        for (int rr = 0; rr < 4; ++rr) {
            float4 x = *(const float4*)&xs[(rg + rr) * 512 + k4 * 4];
            acc[rr] += w.x * x.x + w.y * x.y + w.z * x.z + w.w * x.w;
        }
    }
    const float bb = bias[col];
#pragma unroll
    for (int rr = 0; rr < 4; ++rr)
        hid[(size_t)(r0 + rg + rr) * 1024 + col] = fmaxf(acc[rr] + bb, 0.f);
}

__global__ __launch_bounds__(256)
void mlp2(const float* __restrict__ hid, const float* __restrict__ W,
          const float* __restrict__ bias, const float* __restrict__ xga,
          float* __restrict__ tex)
{
    __shared__ float xs[16 * 1024];
    const int r0 = blockIdx.y * 16;
    const int c0 = blockIdx.x * 64;
    for (int i = threadIdx.x; i < 4096; i += 256)
        ((float4*)xs)[i] = ((const float4*)(hid + (size_t)r0 * 1024))[i];
    __syncthreads();
    const int col = c0 + (threadIdx.x & 63);
    const int rg = (threadIdx.x >> 6) * 4;
    float acc[4] = {0.f, 0.f, 0.f, 0.f};
    const float4* w4 = (const float4*)(W + (size_t)col * 1024);
    for (int k4 = 0; k4 < 256; ++k4) {
        float4 w = w4[k4];
#pragma unroll
        for (int rr = 0; rr < 4; ++rr) {
            float4 x = *(const float4*)&xs[(rg + rr) * 1024 + k4 * 4];
            acc[rr] += w.x * x.x + w.y * x.y + w.z * x.z + w.w * x.w;
        }
    }
    const float bb = bias[col];
#pragma unroll
    for (int rr = 0; rr < 4; ++rr) {
        const int row = r0 + rg + rr;
        tex[(size_t)row * 512 + col] = acc[rr] + bb + xga[(size_t)row * 512 + col];
    }
}

__global__ __launch_bounds__(256)
void norm_out(const float* __restrict__ tex, float* __restrict__ out)
{
    __shared__ float red[256];
    const int b = blockIdx.x;
    const int t = threadIdx.x;
    const float a = tex[b * 512 + t];
    const float c = tex[b * 512 + 256 + t];
    red[t] = a * a + c * c;
    __syncthreads();
    for (int s = 128; s > 0; s >>= 1) {
        if (t < s) red[t] += red[t + s];
        __syncthreads();
    }
    const float inv = 1.f / (sqrtf(red[0]) + 1e-8f);
    out[b * 512 + t] = a * inv;
    out[b * 512 + 256 + t] = c * inv;
}

extern "C" void kernel_launch(void* const* d_in, const int* in_sizes, int n_in,
                              void* d_out, int out_size, void* d_ws, size_t ws_size,
                              hipStream_t stream)
{
    const float* cap = (const float*)d_in[0];
    const int* lengths = (const int*)d_in[1];
    const float* Wq  = (const float*)d_in[2];
    const float* Wk  = (const float*)d_in[3];
    const float* Wv  = (const float*)d_in[4];
    const float* bq  = (const float*)d_in[5];
    const float* bk  = (const float*)d_in[6];
    const float* bv  = (const float*)d_in[7];
    const float* Wfq = (const float*)d_in[8];
    const float* bfq = (const float*)d_in[9];
    const float* Wfk = (const float*)d_in[10];
    const float* bfk = (const float*)d_in[11];
    const float* Wfg = (const float*)d_in[12];
    const float* bfg = (const float*)d_in[13];
    const float* g1  = (const float*)d_in[14];
    const float* b1  = (const float*)d_in[15];
    const float* m1  = (const float*)d_in[16];
    const float* v1  = (const float*)d_in[17];
    const float* Wm1 = (const float*)d_in[30];
    const float* bm1 = (const float*)d_in[31];
    const float* Wm2 = (const float*)d_in[32];
    const float* bm2 = (const float*)d_in[33];
    float* out = (float*)d_out;

    char* w = (char*)d_ws;
    const size_t MB = 1024 * 1024;
    short* capHi = (short*)(w);                // 32MB  -> Ghi after FkG gemm
    short* capLo = (short*)(w + 32 * MB);      // 32MB  -> Glo
    short* KAhi  = (short*)(w + 64 * MB);      // 64MB  [32768,1024]: cols 0-511 K, 512-1023 A=Fq(Q)
    short* KAlo  = (short*)(w + 128 * MB);     // 64MB
    char* wp = w + 192 * MB;
    short* WBhi  = (short*)wp; wp += 1048576;  // [1024,512]: rows 0-511 Wk, 512-1023 Wa
    short* WBlo  = (short*)wp; wp += 1048576;
    short* WfkHi = (short*)wp; wp += 131072;
    short* WfkLo = (short*)wp; wp += 131072;
    short* Wfg2Hi = (short*)wp; wp += 131072;
    short* Wfg2Lo = (short*)wp; wp += 131072;
    float* ba     = (float*)wp; wp += 2048;
    float* qg     = (float*)wp; wp += 262144;
    float* scorep = (float*)wp; wp += 524288;   // [128][2][256][2]
    float* xga    = (float*)wp; wp += 262144;
    float* hid    = (float*)wp; wp += 524288;
    float* tex    = (float*)wp; wp += 262144;
    short* Ghi = capHi;
    short* Glo = capLo;

    // 1. splits: cap, Wk (-> WB rows 0-511), Wfk, Wfg2
    SplitArgs sa;
    sa.src[0] = cap;          sa.hi[0] = capHi;  sa.lo[0] = capLo;  sa.n4[0] = 4194304;
    sa.src[1] = Wk;           sa.hi[1] = WBhi;   sa.lo[1] = WBlo;   sa.n4[1] = 65536;
    sa.src[2] = Wfk;          sa.hi[2] = WfkHi;  sa.lo[2] = WfkLo;  sa.n4[2] = 16384;
    sa.src[3] = Wfg + 65536;  sa.hi[3] = Wfg2Hi; sa.lo[3] = Wfg2Lo; sa.n4[3] = 16384;
    split_multi<<<dim3(4096, 4), 256, 0, stream>>>(sa);

    // 2. composed Wa -> WB rows 512-1023, ba
    compose<<<dim3(512), 256, 0, stream>>>(Wq, bq, Wfq, bfq, WBhi, WBlo, ba);

    // 3. KA fused: [32768,512] x [1024,512]^T -> split [32768,1024]
    gemm_mfma<1><<<dim3(8, 256, 1), 256, 0, stream>>>(
        capHi, capLo, 512, 0, WBhi, WBlo, 512, bk, ba,
        nullptr, nullptr, 0, 0, nullptr, nullptr,
        KAhi, KAlo, 1024, 0, 512);

    // 4. G = (K_h Wfk^T + bfk) * A  -> overwrites cap splits
    gemm_mfma<3><<<dim3(2, 256, 2), 256, 0, stream>>>(
        KAhi, KAlo, 1024, 256, WfkHi, WfkLo, 256, bfk, nullptr,
        KAhi + 512, KAlo + 512, 1024, 256, nullptr, nullptr,
        Ghi, Glo, 512, 256, 256);

    // 5. qg at gathered rows (Q fp32 from cap)
    qg_kernel<<<dim3(256), 256, 0, stream>>>(cap, Ghi, Glo, Wq, bq, Wfg, bfg, lengths, qg);

    // 6. kg gemm with fused score partials (kg never materialized)
    gemm_mfma<4><<<dim3(2, 256, 2), 256, 0, stream>>>(
        Ghi, Glo, 512, 256, Wfg2Hi, Wfg2Lo, 256, bfg + 256, nullptr,
        KAhi, KAlo, 1024, 256, qg, scorep,
        nullptr, nullptr, 0, 0, 256);

    // 7-10. softmax + pV-via-pbar tail, MLP, norm
    attn_tail<<<dim3(128), 256, 0, stream>>>(scorep, cap, lengths, Wv, bv, g1, b1, m1, v1, xga);
    mlp1<<<dim3(16, 8), 256, 0, stream>>>(xga, Wm1, bm1, hid);
    mlp2<<<dim3(8, 8), 256, 0, stream>>>(hid, Wm2, bm2, xga, tex);
    norm_out<<<dim3(128), 256, 0, stream>>>(tex, out);
}

// Round 5
// 408.590 us; speedup vs baseline: 1.0101x; 1.0101x over previous
//
#include <hip/hip_runtime.h>
#include <math.h>

// BS=128, L=256, D=512, H=2, DK=256.
// Conv branches dead (gather idx < 256). Split-bf16 (hi/lo) MFMA GEMMs.
// A = Fq(Q(x)) via composed weight; V GEMM removed via x=(p@cap)@Wv^T+bv.
// KA GEMM: 256^2 tile, 4-slot LDS ring, counted vmcnt(8), setprio.

typedef short bf16x8 __attribute__((ext_vector_type(8)));
typedef float f32x4 __attribute__((ext_vector_type(4)));
typedef short short4v __attribute__((ext_vector_type(4)));

__device__ __forceinline__ short f2bf(float x) {
    union { float f; unsigned u; } c; c.f = x;
    unsigned r = c.u + 0x7FFFu + ((c.u >> 16) & 1u);
    return (short)(r >> 16);
}
__device__ __forceinline__ float bf2f(short h) {
    union { float f; unsigned u; } c; c.u = ((unsigned)(unsigned short)h) << 16;
    return c.f;
}
__device__ __forceinline__ void glds16(const void* g, void* l) {
    __builtin_amdgcn_global_load_lds(
        (const __attribute__((address_space(1))) void*)g,
        (__attribute__((address_space(3))) void*)l, 16, 0, 0);
}

// ---------------- split fp32 -> bf16 hi/lo ----------------
struct SplitArgs {
    const float* src[4];
    short* hi[4];
    short* lo[4];
    int n4[4];
};
__global__ __launch_bounds__(256) void split_multi(SplitArgs a)
{
    const int j = blockIdx.y;
    const float4* s = (const float4*)a.src[j];
    short* hi = a.hi[j];
    short* lo = a.lo[j];
    const int n4 = a.n4[j];
    for (int i = blockIdx.x * 256 + threadIdx.x; i < n4; i += gridDim.x * 256) {
        float4 x = s[i];
        short4v h, l;
        h.x = f2bf(x.x); l.x = f2bf(x.x - bf2f(h.x));
        h.y = f2bf(x.y); l.y = f2bf(x.y - bf2f(h.y));
        h.z = f2bf(x.z); l.z = f2bf(x.z - bf2f(h.z));
        h.w = f2bf(x.w); l.w = f2bf(x.w - bf2f(h.w));
        *(short4v*)&hi[i * 4] = h;
        *(short4v*)&lo[i * 4] = l;
    }
}

// ---------------- composed weight Wa = Wfq @ Wq_h, ba = Wfq@bq_h + bfq ----------------
__global__ __launch_bounds__(256)
void compose(const float* __restrict__ Wq, const float* __restrict__ bq,
             const float* __restrict__ Wfq, const float* __restrict__ bfq,
             short* __restrict__ WBhi, short* __restrict__ WBlo, float* __restrict__ ba)
{
    __shared__ float fq[256];
    __shared__ float redc[256];
    const int op = blockIdx.x;          // 0..511: h = op>>8, o = op&255
    const int h = op >> 8, o = op & 255;
    const int t = threadIdx.x;
    fq[t] = Wfq[o * 256 + t];
    redc[t] = fq[t] * bq[h * 256 + t];
    __syncthreads();
    for (int s = 128; s > 0; s >>= 1) {
        if (t < s) redc[t] += redc[t + s];
        __syncthreads();
    }
    if (t == 0) ba[op] = redc[0] + bfq[o];
    float s0 = 0.f, s1 = 0.f;
    for (int d = 0; d < 256; ++d) {
        const float f = fq[d];
        const float* wr = Wq + (size_t)(h * 256 + d) * 512;
        s0 += f * wr[t];
        s1 += f * wr[t + 256];
    }
    const size_t ro = (size_t)(512 + op) * 512;
    short h0 = f2bf(s0);
    WBhi[ro + t] = h0; WBlo[ro + t] = f2bf(s0 - bf2f(h0));
    short h1 = f2bf(s1);
    WBhi[ro + 256 + t] = h1; WBlo[ro + 256 + t] = f2bf(s1 - bf2f(h1));
}

// ---------------- KA GEMM: 256x256 tile, 4-slot ring, counted vmcnt ----------------
// C[32768,1024] = cap(split) @ WB(split)^T, virtual K = 48 chunks of 32
// chunk vk: pass ph=vk%3 in {hi*hi, lo*hi, hi*lo}, real k0 = (vk/3)*32
__global__ __launch_bounds__(512, 2)
void gemm_ka256(const short* __restrict__ Ahi, const short* __restrict__ Alo,
                const short* __restrict__ Bhi, const short* __restrict__ Blo,
                const float* __restrict__ bias1, const float* __restrict__ bias2,
                short* __restrict__ Chi, short* __restrict__ Clo)
{
    __shared__ short lds[4][16384];   // slot: [0..8191]=A[256][32], [8192..]=B[256][32]
    const int tid = threadIdx.x;
    int bid = blockIdx.y * 4 + blockIdx.x;       // 512 blocks
    bid = (bid & 7) * 64 + (bid >> 3);           // XCD swizzle (512 % 8 == 0)
    const int bm = (bid >> 2) * 256;
    const int bn = (bid & 3) * 256;
    const int lane = tid & 63;
    const int wv = tid >> 6;
    const int wm = wv >> 2, wn = wv & 3;         // 2 x 4 waves
    const int fr = lane & 15, kc = lane >> 4;
    const int srow = tid >> 2;                   // 0..127
    const int se = (tid & 3) * 8;

    auto stage = [&](int vk) {
        const int ph = vk % 3;
        const int k0 = (vk / 3) * 32;
        const short* Ap = (ph == 1) ? Alo : Ahi;
        const short* Bp = (ph == 2) ? Blo : Bhi;
        short* s = (short*)lds[vk & 3];
        glds16(Ap + (size_t)(bm + srow) * 512 + k0 + se,       s + tid * 8);
        glds16(Ap + (size_t)(bm + srow + 128) * 512 + k0 + se, s + (tid + 512) * 8);
        glds16(Bp + (size_t)(bn + srow) * 512 + k0 + se,       s + 8192 + tid * 8);
        glds16(Bp + (size_t)(bn + srow + 128) * 512 + k0 + se, s + 8192 + (tid + 512) * 8);
    };

    f32x4 acc[8][4];
#pragma unroll
    for (int i = 0; i < 8; ++i)
#pragma unroll
        for (int j = 0; j < 4; ++j) acc[i][j] = (f32x4){0.f, 0.f, 0.f, 0.f};

    stage(0); stage(1); stage(2);
    asm volatile("s_waitcnt vmcnt(8)" ::: "memory");
    __builtin_amdgcn_s_barrier();
    asm volatile("" ::: "memory");

    for (int vk = 0; vk < 48; ++vk) {
        const short* s = (const short*)lds[vk & 3];
        bf16x8 af[8], bfv[4];
#pragma unroll
        for (int i = 0; i < 8; ++i)
            af[i] = *(const bf16x8*)&s[(wm * 128 + i * 16 + fr) * 32 + kc * 8];
#pragma unroll
        for (int i = 0; i < 4; ++i)
            bfv[i] = *(const bf16x8*)&s[8192 + (wn * 64 + i * 16 + fr) * 32 + kc * 8];
        if (vk < 45) stage(vk + 3);
        __builtin_amdgcn_s_setprio(1);
#pragma unroll
        for (int mi = 0; mi < 8; ++mi)
#pragma unroll
            for (int ni = 0; ni < 4; ++ni)
                acc[mi][ni] = __builtin_amdgcn_mfma_f32_16x16x32_bf16(af[mi], bfv[ni], acc[mi][ni], 0, 0, 0);
        __builtin_amdgcn_s_setprio(0);
        if (vk < 45)       asm volatile("s_waitcnt vmcnt(8)" ::: "memory");
        else if (vk == 45) asm volatile("s_waitcnt vmcnt(4)" ::: "memory");
        else if (vk == 46) asm volatile("s_waitcnt vmcnt(0)" ::: "memory");
        __builtin_amdgcn_s_barrier();
        asm volatile("" ::: "memory");
    }

    const int colb = bn + wn * 64;
#pragma unroll
    for (int mi = 0; mi < 8; ++mi) {
#pragma unroll
        for (int ni = 0; ni < 4; ++ni) {
#pragma unroll
            for (int r = 0; r < 4; ++r) {
                const int row = bm + wm * 128 + mi * 16 + kc * 4 + r;
                const int col = colb + ni * 16 + fr;
                const float bb = (col < 512) ? bias1[col] : bias2[col - 512];
                const float v = acc[mi][ni][r] + bb;
                const size_t off = (size_t)row * 1024 + col;
                short h = f2bf(v);
                Chi[off] = h;
                Clo[off] = f2bf(v - bf2f(h));
            }
        }
    }
}

// ---------------- 2-phase 128^2 split K-loop (G, kg) ----------------
__device__ __forceinline__ void run_kloop(
    const short* __restrict__ Ahi, const short* __restrict__ Alo, int lda,
    const short* __restrict__ Bhi, const short* __restrict__ Blo, int ldb,
    int K, int bm, int bn, short (*lds)[16384], int tid, f32x4 acc[4][4])
{
    const int lane = tid & 63;
    const int wr = (tid >> 7) & 1;
    const int wc = (tid >> 6) & 1;
    const int fr = lane & 15, kc = lane >> 4;
    const int r0 = tid >> 2;
    const int e0 = (tid & 3) * 8;
    const int NS = K / 32;

    auto stage = [&](int ph, int k0) {
        short* b = lds[ph];
        glds16(Ahi + (size_t)(bm + r0) * lda + k0 + e0,      b + tid * 8);
        glds16(Ahi + (size_t)(bm + r0 + 64) * lda + k0 + e0, b + (tid + 256) * 8);
        glds16(Bhi + (size_t)(bn + r0) * ldb + k0 + e0,      b + 4096 + tid * 8);
        glds16(Bhi + (size_t)(bn + r0 + 64) * ldb + k0 + e0, b + 4096 + (tid + 256) * 8);
        glds16(Alo + (size_t)(bm + r0) * lda + k0 + e0,      b + 8192 + tid * 8);
        glds16(Alo + (size_t)(bm + r0 + 64) * lda + k0 + e0, b + 8192 + (tid + 256) * 8);
        glds16(Blo + (size_t)(bn + r0) * ldb + k0 + e0,      b + 12288 + tid * 8);
        glds16(Blo + (size_t)(bn + r0 + 64) * ldb + k0 + e0, b + 12288 + (tid + 256) * 8);
    };

    stage(0, 0);
    __syncthreads();
    for (int s = 0; s < NS; ++s) {
        if (s + 1 < NS) stage((s + 1) & 1, (s + 1) * 32);
        const short* b = lds[s & 1];
        bf16x8 ah[4], bh[4];
#pragma unroll
        for (int i = 0; i < 4; ++i)
            ah[i] = *(const bf16x8*)&b[(wr * 64 + i * 16 + fr) * 32 + kc * 8];
#pragma unroll
        for (int i = 0; i < 4; ++i)
            bh[i] = *(const bf16x8*)&b[4096 + (wc * 64 + i * 16 + fr) * 32 + kc * 8];
#pragma unroll
        for (int mi = 0; mi < 4; ++mi)
#pragma unroll
            for (int ni = 0; ni < 4; ++ni)
                acc[mi][ni] = __builtin_amdgcn_mfma_f32_16x16x32_bf16(ah[mi], bh[ni], acc[mi][ni], 0, 0, 0);
        bf16x8 al[4], bl[4];
#pragma unroll
        for (int i = 0; i < 4; ++i)
            al[i] = *(const bf16x8*)&b[8192 + (wr * 64 + i * 16 + fr) * 32 + kc * 8];
#pragma unroll
        for (int mi = 0; mi < 4; ++mi)
#pragma unroll
            for (int ni = 0; ni < 4; ++ni)
                acc[mi][ni] = __builtin_amdgcn_mfma_f32_16x16x32_bf16(al[mi], bh[ni], acc[mi][ni], 0, 0, 0);
#pragma unroll
        for (int i = 0; i < 4; ++i)
            bl[i] = *(const bf16x8*)&b[12288 + (wc * 64 + i * 16 + fr) * 32 + kc * 8];
#pragma unroll
        for (int mi = 0; mi < 4; ++mi)
#pragma unroll
            for (int ni = 0; ni < 4; ++ni)
                acc[mi][ni] = __builtin_amdgcn_mfma_f32_16x16x32_bf16(ah[mi], bl[ni], acc[mi][ni], 0, 0, 0);
        __syncthreads();
    }
}

// MODE 3: FkG — split-write of (acc+bias)*(E1+E2)
// MODE 4: kg+score — no write; partial score rows into scorep
template<int MODE>
__global__ __launch_bounds__(256, 2)
void gemm_mfma(const short* __restrict__ Ahi, const short* __restrict__ Alo,
               int lda, int aoff,
               const short* __restrict__ Bhi, const short* __restrict__ Blo, int ldb,
               const float* __restrict__ bias,
               const short* __restrict__ E1, const short* __restrict__ E2, int ldep, int eoff,
               const float* __restrict__ qg, float* __restrict__ scorep,
               short* __restrict__ C0, short* __restrict__ C1, int ldc, int coff,
               int K)
{
    __shared__ short lds[2][16384];
    __shared__ float sp[256];
    const int tid = threadIdx.x;
    const int bm = blockIdx.y * 128;
    const int bn = blockIdx.x * 128;
    const int z = blockIdx.z;

    f32x4 acc[4][4];
#pragma unroll
    for (int i = 0; i < 4; ++i)
#pragma unroll
        for (int j = 0; j < 4; ++j) acc[i][j] = (f32x4){0.f, 0.f, 0.f, 0.f};
    run_kloop(Ahi + (size_t)z * aoff, Alo + (size_t)z * aoff, lda,
              Bhi, Blo, ldb, K, bm, bn, lds, tid, acc);

    const int lane = tid & 63;
    const int wr = (tid >> 7) & 1, wc = (tid >> 6) & 1;
    const int fr = lane & 15, kc = lane >> 4;

    float qgv[4];
    float pt[4][4];
    if (MODE == 4) {
        const int b = bm >> 8;
#pragma unroll
        for (int ni = 0; ni < 4; ++ni)
            qgv[ni] = qg[b * 512 + z * 256 + bn + wc * 64 + ni * 16 + fr];
#pragma unroll
        for (int mi = 0; mi < 4; ++mi)
#pragma unroll
            for (int r = 0; r < 4; ++r) pt[mi][r] = 0.f;
    }

#pragma unroll
    for (int mi = 0; mi < 4; ++mi) {
#pragma unroll
        for (int ni = 0; ni < 4; ++ni) {
#pragma unroll
            for (int r = 0; r < 4; ++r) {
                const int row = bm + wr * 64 + mi * 16 + kc * 4 + r;
                const int col = bn + wc * 64 + ni * 16 + fr;
                float v = acc[mi][ni][r] + bias[col];
                const size_t eoffs = (size_t)row * ldep + z * eoff + col;
                float e = bf2f(E1[eoffs]) + bf2f(E2[eoffs]);
                if (MODE == 3) {
                    float p = v * e;
                    const size_t off = (size_t)row * ldc + z * coff + col;
                    short h = f2bf(p);
                    C0[off] = h;
                    C1[off] = f2bf(p - bf2f(h));
                } else {
                    float kgv = e / (1.f + expf(-v));
                    pt[mi][r] += kgv * qgv[ni];
                }
            }
        }
    }

    if (MODE == 4) {
#pragma unroll
        for (int mi = 0; mi < 4; ++mi) {
#pragma unroll
            for (int r = 0; r < 4; ++r) {
                float p = pt[mi][r];
                p += __shfl_xor(p, 1);
                p += __shfl_xor(p, 2);
                p += __shfl_xor(p, 4);
                p += __shfl_xor(p, 8);
                if (fr == 0) {
                    const int row_local = wr * 64 + mi * 16 + kc * 4 + r;
                    sp[row_local * 2 + wc] = p;
                }
            }
        }
        __syncthreads();
        if (tid < 128) {
            const int row = bm + tid;
            const float s = sp[tid * 2] + sp[tid * 2 + 1];
            const int b = row >> 8, j = row & 255;
            scorep[((size_t)(b * 2 + z) * 256 + j) * 2 + blockIdx.x] = s;
        }
    }
}

// ---------------- qg at gathered rows: Q fp32-exact from cap ----------------
__global__ __launch_bounds__(256)
void qg_kernel(const float* __restrict__ cap,
               const short* __restrict__ Ghi, const short* __restrict__ Glo,
               const float* __restrict__ Wq, const float* __restrict__ bq,
               const float* __restrict__ Wfg, const float* __restrict__ bfg,
               const int* __restrict__ lengths, float* __restrict__ qg)
{
    __shared__ float cr[512];
    __shared__ float gs[256];
    const int b = blockIdx.x >> 1, h = blockIdx.x & 1;
    const int t = threadIdx.x;
    int r = lengths[b] - 1;
    if (r < 0) r = 0;
    if (r > 255) r = 255;
    const size_t base = ((size_t)b * 256 + r) * 512;
    cr[t] = cap[base + t];
    cr[t + 256] = cap[base + 256 + t];
    gs[t] = bf2f(Ghi[base + h * 256 + t]) + bf2f(Glo[base + h * 256 + t]);
    __syncthreads();
    const float4* wq4 = (const float4*)(Wq + (size_t)(h * 256 + t) * 512);
    float q = 0.f;
    for (int k4 = 0; k4 < 128; ++k4) {
        float4 w = wq4[k4];
        q += w.x * cr[k4 * 4 + 0] + w.y * cr[k4 * 4 + 1]
           + w.z * cr[k4 * 4 + 2] + w.w * cr[k4 * 4 + 3];
    }
    q += bq[h * 256 + t];
    const float4* w4 = (const float4*)(Wfg + (size_t)t * 256);
    float a = 0.f;
    for (int k4 = 0; k4 < 64; ++k4) {
        float4 w = w4[k4];
        a += w.x * gs[k4 * 4 + 0] + w.y * gs[k4 * 4 + 1]
           + w.z * gs[k4 * 4 + 2] + w.w * gs[k4 * 4 + 3];
    }
    a += bfg[t];
    qg[b * 512 + h * 256 + t] = q / (1.f + expf(-a));
}

// ---------------- softmax (per sample, both heads) ----------------
__global__ __launch_bounds__(256)
void softmax_p(const float* __restrict__ scorep, float* __restrict__ pn)
{
    __shared__ float sc[512], red[512];
    const int b = blockIdx.x;
    const int t = threadIdx.x;
#pragma unroll
    for (int i = 0; i < 2; ++i) {
        const int o = t + i * 256;
        const int h = o >> 8, j = o & 255;
        const size_t si = ((size_t)(b * 2 + h) * 256 + j) * 2;
        sc[o] = floorf((scorep[si] + scorep[si + 1]) * 0.0625f);
    }
    __syncthreads();
    red[t] = sc[t]; red[t + 256] = sc[t + 256];
    __syncthreads();
    for (int s = 128; s > 0; s >>= 1) {
        if (t < s) {
            red[t] = fmaxf(red[t], red[t + s]);
            red[256 + t] = fmaxf(red[256 + t], red[256 + t + s]);
        }
        __syncthreads();
    }
    const float mx0 = red[0], mx1 = red[256];
    __syncthreads();
    const float e0 = expf(sc[t] - mx0);
    const float e1 = expf(sc[t + 256] - mx1);
    red[t] = e0; red[t + 256] = e1;
    __syncthreads();
    for (int s = 128; s > 0; s >>= 1) {
        if (t < s) { red[t] += red[t + s]; red[256 + t] += red[256 + t + s]; }
        __syncthreads();
    }
    pn[b * 512 + t] = e0 / red[0];
    pn[b * 512 + 256 + t] = e1 / red[256];
}

// ---------------- pbar[b][h][c] = sum_j p[h][j]*cap[b,j,c], parallel ----------------
__global__ __launch_bounds__(256)
void pbar_kernel(const float* __restrict__ pn, const float* __restrict__ cap,
                 float* __restrict__ pbar)
{
    __shared__ float p0s[256], p1s[256], r0[256], r1[256];
    const int b = blockIdx.y, cg = blockIdx.x;
    const int t = threadIdx.x;
    p0s[t] = pn[b * 512 + t];
    p1s[t] = pn[b * 512 + 256 + t];
    __syncthreads();
    const int c = cg * 64 + (t & 63);
    const int jg = t >> 6;
    float a0 = 0.f, a1 = 0.f;
    for (int j = jg * 64; j < jg * 64 + 64; ++j) {
        const float cv = cap[((size_t)(b * 256 + j)) * 512 + c];
        a0 += p0s[j] * cv;
        a1 += p1s[j] * cv;
    }
    r0[t] = a0; r1[t] = a1;
    __syncthreads();
    if (t < 64) {
        const float s0 = r0[t] + r0[t + 64] + r0[t + 128] + r0[t + 192];
        const float s1 = r1[t] + r1[t + 64] + r1[t + 128] + r1[t + 192];
        pbar[b * 1024 + cg * 64 + t] = s0;
        pbar[b * 1024 + 512 + cg * 64 + t] = s1;
    }
}

// ---------------- x = pbar@Wv^T + bv, BN1, residual ----------------
__global__ __launch_bounds__(256)
void bnx_kernel(const float* __restrict__ pbar, const float* __restrict__ cap,
                const int* __restrict__ lengths,
                const float* __restrict__ Wv, const float* __restrict__ bv,
                const float* __restrict__ g1, const float* __restrict__ b1,
                const float* __restrict__ m1, const float* __restrict__ v1,
                float* __restrict__ xga)
{
    __shared__ float pb[1024];
    const int b = blockIdx.x;
    const int t = threadIdx.x;
    int r = lengths[b] - 1;
    if (r < 0) r = 0;
    if (r > 255) r = 255;
    const size_t base = ((size_t)b * 256 + r) * 512;
    pb[t] = pbar[b * 1024 + t];
    pb[t + 256] = pbar[b * 1024 + 256 + t];
    pb[t + 512] = pbar[b * 1024 + 512 + t];
    pb[t + 768] = pbar[b * 1024 + 768 + t];
    __syncthreads();
    float x0 = 0.f, x1 = 0.f;
    {
        const float4* w4 = (const float4*)(Wv + (size_t)t * 512);
        for (int k4 = 0; k4 < 128; ++k4) {
            float4 w = w4[k4];
            x0 += w.x * pb[k4 * 4 + 0] + w.y * pb[k4 * 4 + 1]
                + w.z * pb[k4 * 4 + 2] + w.w * pb[k4 * 4 + 3];
        }
        x0 += bv[t];
    }
    {
        const float4* w4 = (const float4*)(Wv + (size_t)(t + 256) * 512);
        for (int k4 = 0; k4 < 128; ++k4) {
            float4 w = w4[k4];
            x1 += w.x * pb[512 + k4 * 4 + 0] + w.y * pb[512 + k4 * 4 + 1]
                + w.z * pb[512 + k4 * 4 + 2] + w.w * pb[512 + k4 * 4 + 3];
        }
        x1 += bv[t + 256];
    }
    const int c0 = t, c1 = t + 256;
    const float s0 = g1[c0] / sqrtf(v1[c0] + 1e-5f);
    const float s1 = g1[c1] / sqrtf(v1[c1] + 1e-5f);
    xga[b * 512 + c0] = cap[base + c0] + (x0 - m1[c0]) * s0 + b1[c0];
    xga[b * 512 + c1] = cap[base + c1] + (x1 - m1[c1]) * s1 + b1[c1];
}

// ---------------- MLP strip GEMMs (weights read once) ----------------
__global__ __launch_bounds__(256)
void mlp1(const float* __restrict__ xga, const float* __restrict__ W,
          const float* __restrict__ bias, float* __restrict__ hid)
{
    __shared__ float xs[16 * 512];
    const int r0 = blockIdx.y * 16;
    const int c0 = blockIdx.x * 64;
    for (int i = threadIdx.x; i < 2048; i += 256)
        ((float4*)xs)[i] = ((const float4*)(xga + (size_t)r0 * 512))[i];
    __syncthreads();
    const int col = c0 + (threadIdx.x & 63);
    const int rg = (threadIdx.x >> 6) * 4;
    float acc[4] = {0.f, 0.f, 0.f, 0.f};
    const float4* w4 = (const float4*)(W + (size_t)col * 512);
    for (int k4 = 0; k4 < 128; ++k4) {
        float4 w = w4[k4];
#pragma unroll
        for (int rr = 0; rr < 4; ++rr) {
            float4 x = *(const float4*)&xs[(rg + rr) * 512 + k4 * 4];
            acc[rr] += w.x * x.x + w.y * x.y + w.z * x.z + w.w * x.w;
        }
    }
    const float bb = bias[col];
#pragma unroll
    for (int rr = 0; rr < 4; ++rr)
        hid[(size_t)(r0 + rg + rr) * 1024 + col] = fmaxf(acc[rr] + bb, 0.f);
}

__global__ __launch_bounds__(256)
void mlp2(const float* __restrict__ hid, const float* __restrict__ W,
          const float* __restrict__ bias, const float* __restrict__ xga,
          float* __restrict__ tex)
{
    __shared__ float xs[16 * 1024];
    const int r0 = blockIdx.y * 16;
    const int c0 = blockIdx.x * 64;
    for (int i = threadIdx.x; i < 4096; i += 256)
        ((float4*)xs)[i] = ((const float4*)(hid + (size_t)r0 * 1024))[i];
    __syncthreads();
    const int col = c0 + (threadIdx.x & 63);
    const int rg = (threadIdx.x >> 6) * 4;
    float acc[4] = {0.f, 0.f, 0.f, 0.f};
    const float4* w4 = (const float4*)(W + (size_t)col * 1024);
    for (int k4 = 0; k4 < 256; ++k4) {
        float4 w = w4[k4];
#pragma unroll
        for (int rr = 0; rr < 4; ++rr) {
            float4 x = *(const float4*)&xs[(rg + rr) * 1024 + k4 * 4];
            acc[rr] += w.x * x.x + w.y * x.y + w.z * x.z + w.w * x.w;
        }
    }
    const float bb = bias[col];
#pragma unroll
    for (int rr = 0; rr < 4; ++rr) {
        const int row = r0 + rg + rr;
        tex[(size_t)row * 512 + col] = acc[rr] + bb + xga[(size_t)row * 512 + col];
    }
}

__global__ __launch_bounds__(256)
void norm_out(const float* __restrict__ tex, float* __restrict__ out)
{
    __shared__ float red[256];
    const int b = blockIdx.x;
    const int t = threadIdx.x;
    const float a = tex[b * 512 + t];
    const float c = tex[b * 512 + 256 + t];
    red[t] = a * a + c * c;
    __syncthreads();
    for (int s = 128; s > 0; s >>= 1) {
        if (t < s) red[t] += red[t + s];
        __syncthreads();
    }
    const float inv = 1.f / (sqrtf(red[0]) + 1e-8f);
    out[b * 512 + t] = a * inv;
    out[b * 512 + 256 + t] = c * inv;
}

extern "C" void kernel_launch(void* const* d_in, const int* in_sizes, int n_in,
                              void* d_out, int out_size, void* d_ws, size_t ws_size,
                              hipStream_t stream)
{
    const float* cap = (const float*)d_in[0];
    const int* lengths = (const int*)d_in[1];
    const float* Wq  = (const float*)d_in[2];
    const float* Wk  = (const float*)d_in[3];
    const float* Wv  = (const float*)d_in[4];
    const float* bq  = (const float*)d_in[5];
    const float* bk  = (const float*)d_in[6];
    const float* bv  = (const float*)d_in[7];
    const float* Wfq = (const float*)d_in[8];
    const float* bfq = (const float*)d_in[9];
    const float* Wfk = (const float*)d_in[10];
    const float* bfk = (const float*)d_in[11];
    const float* Wfg = (const float*)d_in[12];
    const float* bfg = (const float*)d_in[13];
    const float* g1  = (const float*)d_in[14];
    const float* b1  = (const float*)d_in[15];
    const float* m1  = (const float*)d_in[16];
    const float* v1  = (const float*)d_in[17];
    const float* Wm1 = (const float*)d_in[30];
    const float* bm1 = (const float*)d_in[31];
    const float* Wm2 = (const float*)d_in[32];
    const float* bm2 = (const float*)d_in[33];
    float* out = (float*)d_out;

    char* w = (char*)d_ws;
    const size_t MB = 1024 * 1024;
    short* capHi = (short*)(w);                // 32MB  -> Ghi after FkG gemm
    short* capLo = (short*)(w + 32 * MB);      // 32MB  -> Glo
    short* KAhi  = (short*)(w + 64 * MB);      // 64MB  [32768,1024]: cols 0-511 K, 512-1023 A=Fq(Q)
    short* KAlo  = (short*)(w + 128 * MB);     // 64MB
    char* wp = w + 192 * MB;
    short* WBhi  = (short*)wp; wp += 1048576;  // [1024,512]: rows 0-511 Wk, 512-1023 Wa
    short* WBlo  = (short*)wp; wp += 1048576;
    short* WfkHi = (short*)wp; wp += 131072;
    short* WfkLo = (short*)wp; wp += 131072;
    short* Wfg2Hi = (short*)wp; wp += 131072;
    short* Wfg2Lo = (short*)wp; wp += 131072;
    float* ba     = (float*)wp; wp += 2048;
    float* qg     = (float*)wp; wp += 262144;
    float* scorep = (float*)wp; wp += 524288;   // [128][2][256][2]
    float* pn     = (float*)wp; wp += 262144;   // [128][2][256]
    float* pbar   = (float*)wp; wp += 524288;   // [128][2][512]
    float* xga    = (float*)wp; wp += 262144;
    float* hid    = (float*)wp; wp += 524288;
    float* tex    = (float*)wp; wp += 262144;
    short* Ghi = capHi;
    short* Glo = capLo;

    // 1. splits: cap, Wk (-> WB rows 0-511), Wfk, Wfg2
    SplitArgs sa;
    sa.src[0] = cap;          sa.hi[0] = capHi;  sa.lo[0] = capLo;  sa.n4[0] = 4194304;
    sa.src[1] = Wk;           sa.hi[1] = WBhi;   sa.lo[1] = WBlo;   sa.n4[1] = 65536;
    sa.src[2] = Wfk;          sa.hi[2] = WfkHi;  sa.lo[2] = WfkLo;  sa.n4[2] = 16384;
    sa.src[3] = Wfg + 65536;  sa.hi[3] = Wfg2Hi; sa.lo[3] = Wfg2Lo; sa.n4[3] = 16384;
    split_multi<<<dim3(4096, 4), 256, 0, stream>>>(sa);

    // 2. composed Wa -> WB rows 512-1023, ba
    compose<<<dim3(512), 256, 0, stream>>>(Wq, bq, Wfq, bfq, WBhi, WBlo, ba);

    // 3. KA fused: 256^2-tile ring kernel
    gemm_ka256<<<dim3(4, 128), 512, 0, stream>>>(capHi, capLo, WBhi, WBlo, bk, ba, KAhi, KAlo);

    // 4. G = (K_h Wfk^T + bfk) * A  -> overwrites cap splits
    gemm_mfma<3><<<dim3(2, 256, 2), 256, 0, stream>>>(
        KAhi, KAlo, 1024, 256, WfkHi, WfkLo, 256, bfk,
        KAhi + 512, KAlo + 512, 1024, 256, nullptr, nullptr,
        Ghi, Glo, 512, 256, 256);

    // 5. qg at gathered rows (Q fp32 from cap)
    qg_kernel<<<dim3(256), 256, 0, stream>>>(cap, Ghi, Glo, Wq, bq, Wfg, bfg, lengths, qg);

    // 6. kg gemm with fused score partials (kg never materialized)
    gemm_mfma<4><<<dim3(2, 256, 2), 256, 0, stream>>>(
        Ghi, Glo, 512, 256, Wfg2Hi, Wfg2Lo, 256, bfg + 256,
        KAhi, KAlo, 1024, 256, qg, scorep,
        nullptr, nullptr, 0, 0, 256);

    // 7-9. softmax, parallel pbar, BN/residual
    softmax_p<<<dim3(128), 256, 0, stream>>>(scorep, pn);
    pbar_kernel<<<dim3(8, 128), 256, 0, stream>>>(pn, cap, pbar);
    bnx_kernel<<<dim3(128), 256, 0, stream>>>(pbar, cap, lengths, Wv, bv, g1, b1, m1, v1, xga);

    // 10-12. MLP, norm
    mlp1<<<dim3(16, 8), 256, 0, stream>>>(xga, Wm1, bm1, hid);
    mlp2<<<dim3(8, 8), 256, 0, stream>>>(hid, Wm2, bm2, xga, tex);
    norm_out<<<dim3(128), 256, 0, stream>>>(tex, out);
}

// Round 6
// 397.931 us; speedup vs baseline: 1.0371x; 1.0268x over previous
//
#include <hip/hip_runtime.h>
#include <math.h>

// BS=128, L=256, D=512, H=2, DK=256.
// Conv branches dead (gather idx < 256). Split-bf16 (hi/lo) MFMA GEMMs.
// A = Fq(Q(x)) via composed weight; V GEMM removed via x=(p@cap)@Wv^T+bv.
// KA GEMM: 256^2 tile, 4-slot LDS ring, counted vmcnt, T2 XOR swizzle
// (linear LDS dest + pre-swizzled global source + swizzled ds_read).

typedef short bf16x8 __attribute__((ext_vector_type(8)));
typedef float f32x4 __attribute__((ext_vector_type(4)));
typedef short short4v __attribute__((ext_vector_type(4)));

__device__ __forceinline__ short f2bf(float x) {
    union { float f; unsigned u; } c; c.f = x;
    unsigned r = c.u + 0x7FFFu + ((c.u >> 16) & 1u);
    return (short)(r >> 16);
}
__device__ __forceinline__ float bf2f(short h) {
    union { float f; unsigned u; } c; c.u = ((unsigned)(unsigned short)h) << 16;
    return c.f;
}
__device__ __forceinline__ void glds16(const void* g, void* l) {
    __builtin_amdgcn_global_load_lds(
        (const __attribute__((address_space(1))) void*)g,
        (__attribute__((address_space(3))) void*)l, 16, 0, 0);
}

// ---------------- split fp32 -> bf16 hi/lo ----------------
struct SplitArgs {
    const float* src[4];
    short* hi[4];
    short* lo[4];
    int n4[4];
};
__global__ __launch_bounds__(256) void split_multi(SplitArgs a)
{
    const int j = blockIdx.y;
    const float4* s = (const float4*)a.src[j];
    short* hi = a.hi[j];
    short* lo = a.lo[j];
    const int n4 = a.n4[j];
    for (int i = blockIdx.x * 256 + threadIdx.x; i < n4; i += gridDim.x * 256) {
        float4 x = s[i];
        short4v h, l;
        h.x = f2bf(x.x); l.x = f2bf(x.x - bf2f(h.x));
        h.y = f2bf(x.y); l.y = f2bf(x.y - bf2f(h.y));
        h.z = f2bf(x.z); l.z = f2bf(x.z - bf2f(h.z));
        h.w = f2bf(x.w); l.w = f2bf(x.w - bf2f(h.w));
        *(short4v*)&hi[i * 4] = h;
        *(short4v*)&lo[i * 4] = l;
    }
}

// ---------------- composed weight Wa = Wfq @ Wq_h, ba = Wfq@bq_h + bfq ----------------
__global__ __launch_bounds__(256)
void compose(const float* __restrict__ Wq, const float* __restrict__ bq,
             const float* __restrict__ Wfq, const float* __restrict__ bfq,
             short* __restrict__ WBhi, short* __restrict__ WBlo, float* __restrict__ ba)
{
    __shared__ float fq[256];
    __shared__ float redc[256];
    const int op = blockIdx.x;          // 0..511: h = op>>8, o = op&255
    const int h = op >> 8, o = op & 255;
    const int t = threadIdx.x;
    fq[t] = Wfq[o * 256 + t];
    redc[t] = fq[t] * bq[h * 256 + t];
    __syncthreads();
    for (int s = 128; s > 0; s >>= 1) {
        if (t < s) redc[t] += redc[t + s];
        __syncthreads();
    }
    if (t == 0) ba[op] = redc[0] + bfq[o];
    float s0 = 0.f, s1 = 0.f;
    for (int d = 0; d < 256; ++d) {
        const float f = fq[d];
        const float* wr = Wq + (size_t)(h * 256 + d) * 512;
        s0 += f * wr[t];
        s1 += f * wr[t + 256];
    }
    const size_t ro = (size_t)(512 + op) * 512;
    short h0 = f2bf(s0);
    WBhi[ro + t] = h0; WBlo[ro + t] = f2bf(s0 - bf2f(h0));
    short h1 = f2bf(s1);
    WBhi[ro + 256 + t] = h1; WBlo[ro + 256 + t] = f2bf(s1 - bf2f(h1));
}

// ---------------- KA GEMM: 256x256 tile, 4-slot ring, counted vmcnt, T2 swizzle ----------------
// C[32768,1024] = cap(split) @ WB(split)^T, virtual K = 48 chunks of 32
// chunk vk: pass ph=vk%3 in {hi*hi, lo*hi, hi*lo}, real k0 = (vk/3)*32
__global__ __launch_bounds__(512, 2)
void gemm_ka256(const short* __restrict__ Ahi, const short* __restrict__ Alo,
                const short* __restrict__ Bhi, const short* __restrict__ Blo,
                const float* __restrict__ bias1, const float* __restrict__ bias2,
                short* __restrict__ Chi, short* __restrict__ Clo)
{
    __shared__ short lds[4][16384];   // slot: [0..8191]=A[256][32], [8192..]=B[256][32]
    const int tid = threadIdx.x;
    int bid = blockIdx.y * 4 + blockIdx.x;       // 512 blocks
    bid = (bid & 7) * 64 + (bid >> 3);           // XCD swizzle (512 % 8 == 0)
    const int bm = (bid >> 2) * 256;
    const int bn = (bid & 3) * 256;
    const int lane = tid & 63;
    const int wv = tid >> 6;
    const int wm = wv >> 2, wn = wv & 3;         // 2 x 4 waves
    const int fr = lane & 15, kc = lane >> 4;
    const int srow = tid >> 2;                   // 0..127
    // T2: pre-swizzled global source column-group; LDS dest stays linear
    const int se = (((tid & 3) ^ ((srow >> 1) & 3))) * 8;

    auto stage = [&](int vk) {
        const int ph = vk % 3;
        const int k0 = (vk / 3) * 32;
        const short* Ap = (ph == 1) ? Alo : Ahi;
        const short* Bp = (ph == 2) ? Blo : Bhi;
        short* s = (short*)lds[vk & 3];
        glds16(Ap + (size_t)(bm + srow) * 512 + k0 + se,       s + tid * 8);
        glds16(Ap + (size_t)(bm + srow + 128) * 512 + k0 + se, s + (tid + 512) * 8);
        glds16(Bp + (size_t)(bn + srow) * 512 + k0 + se,       s + 8192 + tid * 8);
        glds16(Bp + (size_t)(bn + srow + 128) * 512 + k0 + se, s + 8192 + (tid + 512) * 8);
    };

    f32x4 acc[8][4];
#pragma unroll
    for (int i = 0; i < 8; ++i)
#pragma unroll
        for (int j = 0; j < 4; ++j) acc[i][j] = (f32x4){0.f, 0.f, 0.f, 0.f};

    stage(0); stage(1); stage(2);
    asm volatile("s_waitcnt vmcnt(8)" ::: "memory");
    __builtin_amdgcn_s_barrier();
    asm volatile("" ::: "memory");

    const int rsw = (fr >> 1) & 3;               // read-side swizzle (row terms drop mod 4)
    const int kce = (kc ^ rsw) * 8;

    for (int vk = 0; vk < 48; ++vk) {
        const short* s = (const short*)lds[vk & 3];
        bf16x8 af[8], bfv[4];
#pragma unroll
        for (int i = 0; i < 8; ++i)
            af[i] = *(const bf16x8*)&s[(wm * 128 + i * 16 + fr) * 32 + kce];
#pragma unroll
        for (int i = 0; i < 4; ++i)
            bfv[i] = *(const bf16x8*)&s[8192 + (wn * 64 + i * 16 + fr) * 32 + kce];
        if (vk < 45) stage(vk + 3);
        __builtin_amdgcn_s_setprio(1);
#pragma unroll
        for (int mi = 0; mi < 8; ++mi)
#pragma unroll
            for (int ni = 0; ni < 4; ++ni)
                acc[mi][ni] = __builtin_amdgcn_mfma_f32_16x16x32_bf16(af[mi], bfv[ni], acc[mi][ni], 0, 0, 0);
        __builtin_amdgcn_s_setprio(0);
        if (vk < 45)       asm volatile("s_waitcnt vmcnt(8)" ::: "memory");
        else if (vk == 45) asm volatile("s_waitcnt vmcnt(4)" ::: "memory");
        else if (vk == 46) asm volatile("s_waitcnt vmcnt(0)" ::: "memory");
        __builtin_amdgcn_s_barrier();
        asm volatile("" ::: "memory");
    }

    const int colb = bn + wn * 64;
#pragma unroll
    for (int mi = 0; mi < 8; ++mi) {
#pragma unroll
        for (int ni = 0; ni < 4; ++ni) {
#pragma unroll
            for (int r = 0; r < 4; ++r) {
                const int row = bm + wm * 128 + mi * 16 + kc * 4 + r;
                const int col = colb + ni * 16 + fr;
                const float bb = (col < 512) ? bias1[col] : bias2[col - 512];
                const float v = acc[mi][ni][r] + bb;
                const size_t off = (size_t)row * 1024 + col;
                short h = f2bf(v);
                Chi[off] = h;
                Clo[off] = f2bf(v - bf2f(h));
            }
        }
    }
}

// ---------------- 2-phase 128^2 split K-loop (G, kg), T2-swizzled ----------------
__device__ __forceinline__ void run_kloop(
    const short* __restrict__ Ahi, const short* __restrict__ Alo, int lda,
    const short* __restrict__ Bhi, const short* __restrict__ Blo, int ldb,
    int K, int bm, int bn, short (*lds)[16384], int tid, f32x4 acc[4][4])
{
    const int lane = tid & 63;
    const int wr = (tid >> 7) & 1;
    const int wc = (tid >> 6) & 1;
    const int fr = lane & 15, kc = lane >> 4;
    const int r0 = tid >> 2;
    const int e0 = (((tid & 3) ^ ((r0 >> 1) & 3))) * 8;   // pre-swizzled source group
    const int NS = K / 32;

    auto stage = [&](int ph, int k0) {
        short* b = lds[ph];
        glds16(Ahi + (size_t)(bm + r0) * lda + k0 + e0,      b + tid * 8);
        glds16(Ahi + (size_t)(bm + r0 + 64) * lda + k0 + e0, b + (tid + 256) * 8);
        glds16(Bhi + (size_t)(bn + r0) * ldb + k0 + e0,      b + 4096 + tid * 8);
        glds16(Bhi + (size_t)(bn + r0 + 64) * ldb + k0 + e0, b + 4096 + (tid + 256) * 8);
        glds16(Alo + (size_t)(bm + r0) * lda + k0 + e0,      b + 8192 + tid * 8);
        glds16(Alo + (size_t)(bm + r0 + 64) * lda + k0 + e0, b + 8192 + (tid + 256) * 8);
        glds16(Blo + (size_t)(bn + r0) * ldb + k0 + e0,      b + 12288 + tid * 8);
        glds16(Blo + (size_t)(bn + r0 + 64) * ldb + k0 + e0, b + 12288 + (tid + 256) * 8);
    };

    const int kce = (kc ^ ((fr >> 1) & 3)) * 8;           // read-side swizzle

    stage(0, 0);
    __syncthreads();
    for (int s = 0; s < NS; ++s) {
        if (s + 1 < NS) stage((s + 1) & 1, (s + 1) * 32);
        const short* b = lds[s & 1];
        bf16x8 ah[4], bh[4];
#pragma unroll
        for (int i = 0; i < 4; ++i)
            ah[i] = *(const bf16x8*)&b[(wr * 64 + i * 16 + fr) * 32 + kce];
#pragma unroll
        for (int i = 0; i < 4; ++i)
            bh[i] = *(const bf16x8*)&b[4096 + (wc * 64 + i * 16 + fr) * 32 + kce];
#pragma unroll
        for (int mi = 0; mi < 4; ++mi)
#pragma unroll
            for (int ni = 0; ni < 4; ++ni)
                acc[mi][ni] = __builtin_amdgcn_mfma_f32_16x16x32_bf16(ah[mi], bh[ni], acc[mi][ni], 0, 0, 0);
        bf16x8 al[4], bl[4];
#pragma unroll
        for (int i = 0; i < 4; ++i)
            al[i] = *(const bf16x8*)&b[8192 + (wr * 64 + i * 16 + fr) * 32 + kce];
#pragma unroll
        for (int mi = 0; mi < 4; ++mi)
#pragma unroll
            for (int ni = 0; ni < 4; ++ni)
                acc[mi][ni] = __builtin_amdgcn_mfma_f32_16x16x32_bf16(al[mi], bh[ni], acc[mi][ni], 0, 0, 0);
#pragma unroll
        for (int i = 0; i < 4; ++i)
            bl[i] = *(const bf16x8*)&b[12288 + (wc * 64 + i * 16 + fr) * 32 + kce];
#pragma unroll
        for (int mi = 0; mi < 4; ++mi)
#pragma unroll
            for (int ni = 0; ni < 4; ++ni)
                acc[mi][ni] = __builtin_amdgcn_mfma_f32_16x16x32_bf16(ah[mi], bl[ni], acc[mi][ni], 0, 0, 0);
        __syncthreads();
    }
}

// MODE 3: FkG — split-write of (acc+bias)*(E1+E2)
// MODE 4: kg+score — no write; partial score rows into scorep
template<int MODE>
__global__ __launch_bounds__(256, 2)
void gemm_mfma(const short* __restrict__ Ahi, const short* __restrict__ Alo,
               int lda, int aoff,
               const short* __restrict__ Bhi, const short* __restrict__ Blo, int ldb,
               const float* __restrict__ bias,
               const short* __restrict__ E1, const short* __restrict__ E2, int ldep, int eoff,
               const float* __restrict__ qg, float* __restrict__ scorep,
               short* __restrict__ C0, short* __restrict__ C1, int ldc, int coff,
               int K)
{
    __shared__ short lds[2][16384];
    __shared__ float sp[256];
    const int tid = threadIdx.x;
    const int bm = blockIdx.y * 128;
    const int bn = blockIdx.x * 128;
    const int z = blockIdx.z;

    f32x4 acc[4][4];
#pragma unroll
    for (int i = 0; i < 4; ++i)
#pragma unroll
        for (int j = 0; j < 4; ++j) acc[i][j] = (f32x4){0.f, 0.f, 0.f, 0.f};
    run_kloop(Ahi + (size_t)z * aoff, Alo + (size_t)z * aoff, lda,
              Bhi, Blo, ldb, K, bm, bn, lds, tid, acc);

    const int lane = tid & 63;
    const int wr = (tid >> 7) & 1, wc = (tid >> 6) & 1;
    const int fr = lane & 15, kc = lane >> 4;

    float qgv[4];
    float pt[4][4];
    if (MODE == 4) {
        const int b = bm >> 8;
#pragma unroll
        for (int ni = 0; ni < 4; ++ni)
            qgv[ni] = qg[b * 512 + z * 256 + bn + wc * 64 + ni * 16 + fr];
#pragma unroll
        for (int mi = 0; mi < 4; ++mi)
#pragma unroll
            for (int r = 0; r < 4; ++r) pt[mi][r] = 0.f;
    }

#pragma unroll
    for (int mi = 0; mi < 4; ++mi) {
#pragma unroll
        for (int ni = 0; ni < 4; ++ni) {
#pragma unroll
            for (int r = 0; r < 4; ++r) {
                const int row = bm + wr * 64 + mi * 16 + kc * 4 + r;
                const int col = bn + wc * 64 + ni * 16 + fr;
                float v = acc[mi][ni][r] + bias[col];
                const size_t eoffs = (size_t)row * ldep + z * eoff + col;
                float e = bf2f(E1[eoffs]) + bf2f(E2[eoffs]);
                if (MODE == 3) {
                    float p = v * e;
                    const size_t off = (size_t)row * ldc + z * coff + col;
                    short h = f2bf(p);
                    C0[off] = h;
                    C1[off] = f2bf(p - bf2f(h));
                } else {
                    float kgv = e / (1.f + expf(-v));
                    pt[mi][r] += kgv * qgv[ni];
                }
            }
        }
    }

    if (MODE == 4) {
#pragma unroll
        for (int mi = 0; mi < 4; ++mi) {
#pragma unroll
            for (int r = 0; r < 4; ++r) {
                float p = pt[mi][r];
                p += __shfl_xor(p, 1);
                p += __shfl_xor(p, 2);
                p += __shfl_xor(p, 4);
                p += __shfl_xor(p, 8);
                if (fr == 0) {
                    const int row_local = wr * 64 + mi * 16 + kc * 4 + r;
                    sp[row_local * 2 + wc] = p;
                }
            }
        }
        __syncthreads();
        if (tid < 128) {
            const int row = bm + tid;
            const float s = sp[tid * 2] + sp[tid * 2 + 1];
            const int b = row >> 8, j = row & 255;
            scorep[((size_t)(b * 2 + z) * 256 + j) * 2 + blockIdx.x] = s;
        }
    }
}

// ---------------- qg at gathered rows: Q fp32-exact from cap ----------------
__global__ __launch_bounds__(256)
void qg_kernel(const float* __restrict__ cap,
               const short* __restrict__ Ghi, const short* __restrict__ Glo,
               const float* __restrict__ Wq, const float* __restrict__ bq,
               const float* __restrict__ Wfg, const float* __restrict__ bfg,
               const int* __restrict__ lengths, float* __restrict__ qg)
{
    __shared__ float cr[512];
    __shared__ float gs[256];
    const int b = blockIdx.x >> 1, h = blockIdx.x & 1;
    const int t = threadIdx.x;
    int r = lengths[b] - 1;
    if (r < 0) r = 0;
    if (r > 255) r = 255;
    const size_t base = ((size_t)b * 256 + r) * 512;
    cr[t] = cap[base + t];
    cr[t + 256] = cap[base + 256 + t];
    gs[t] = bf2f(Ghi[base + h * 256 + t]) + bf2f(Glo[base + h * 256 + t]);
    __syncthreads();
    const float4* wq4 = (const float4*)(Wq + (size_t)(h * 256 + t) * 512);
    float q = 0.f;
    for (int k4 = 0; k4 < 128; ++k4) {
        float4 w = wq4[k4];
        q += w.x * cr[k4 * 4 + 0] + w.y * cr[k4 * 4 + 1]
           + w.z * cr[k4 * 4 + 2] + w.w * cr[k4 * 4 + 3];
    }
    q += bq[h * 256 + t];
    const float4* w4 = (const float4*)(Wfg + (size_t)t * 256);
    float a = 0.f;
    for (int k4 = 0; k4 < 64; ++k4) {
        float4 w = w4[k4];
        a += w.x * gs[k4 * 4 + 0] + w.y * gs[k4 * 4 + 1]
           + w.z * gs[k4 * 4 + 2] + w.w * gs[k4 * 4 + 3];
    }
    a += bfg[t];
    qg[b * 512 + h * 256 + t] = q / (1.f + expf(-a));
}

// ---------------- softmax (per sample, both heads) ----------------
__global__ __launch_bounds__(256)
void softmax_p(const float* __restrict__ scorep, float* __restrict__ pn)
{
    __shared__ float sc[512], red[512];
    const int b = blockIdx.x;
    const int t = threadIdx.x;
#pragma unroll
    for (int i = 0; i < 2; ++i) {
        const int o = t + i * 256;
        const int h = o >> 8, j = o & 255;
        const size_t si = ((size_t)(b * 2 + h) * 256 + j) * 2;
        sc[o] = floorf((scorep[si] + scorep[si + 1]) * 0.0625f);
    }
    __syncthreads();
    red[t] = sc[t]; red[t + 256] = sc[t + 256];
    __syncthreads();
    for (int s = 128; s > 0; s >>= 1) {
        if (t < s) {
            red[t] = fmaxf(red[t], red[t + s]);
            red[256 + t] = fmaxf(red[256 + t], red[256 + t + s]);
        }
        __syncthreads();
    }
    const float mx0 = red[0], mx1 = red[256];
    __syncthreads();
    const float e0 = expf(sc[t] - mx0);
    const float e1 = expf(sc[t + 256] - mx1);
    red[t] = e0; red[t + 256] = e1;
    __syncthreads();
    for (int s = 128; s > 0; s >>= 1) {
        if (t < s) { red[t] += red[t + s]; red[256 + t] += red[256 + t + s]; }
        __syncthreads();
    }
    pn[b * 512 + t] = e0 / red[0];
    pn[b * 512 + 256 + t] = e1 / red[256];
}

// ---------------- pbar[b][h][c] = sum_j p[h][j]*cap[b,j,c], parallel ----------------
__global__ __launch_bounds__(256)
void pbar_kernel(const float* __restrict__ pn, const float* __restrict__ cap,
                 float* __restrict__ pbar)
{
    __shared__ float p0s[256], p1s[256], r0[256], r1[256];
    const int b = blockIdx.y, cg = blockIdx.x;
    const int t = threadIdx.x;
    p0s[t] = pn[b * 512 + t];
    p1s[t] = pn[b * 512 + 256 + t];
    __syncthreads();
    const int c = cg * 64 + (t & 63);
    const int jg = t >> 6;
    float a0 = 0.f, a1 = 0.f;
    for (int j = jg * 64; j < jg * 64 + 64; ++j) {
        const float cv = cap[((size_t)(b * 256 + j)) * 512 + c];
        a0 += p0s[j] * cv;
        a1 += p1s[j] * cv;
    }
    r0[t] = a0; r1[t] = a1;
    __syncthreads();
    if (t < 64) {
        const float s0 = r0[t] + r0[t + 64] + r0[t + 128] + r0[t + 192];
        const float s1 = r1[t] + r1[t + 64] + r1[t + 128] + r1[t + 192];
        pbar[b * 1024 + cg * 64 + t] = s0;
        pbar[b * 1024 + 512 + cg * 64 + t] = s1;
    }
}

// ---------------- x = pbar@Wv^T + bv, BN1, residual ----------------
__global__ __launch_bounds__(256)
void bnx_kernel(const float* __restrict__ pbar, const float* __restrict__ cap,
                const int* __restrict__ lengths,
                const float* __restrict__ Wv, const float* __restrict__ bv,
                const float* __restrict__ g1, const float* __restrict__ b1,
                const float* __restrict__ m1, const float* __restrict__ v1,
                float* __restrict__ xga)
{
    __shared__ float pb[1024];
    const int b = blockIdx.x;
    const int t = threadIdx.x;
    int r = lengths[b] - 1;
    if (r < 0) r = 0;
    if (r > 255) r = 255;
    const size_t base = ((size_t)b * 256 + r) * 512;
    pb[t] = pbar[b * 1024 + t];
    pb[t + 256] = pbar[b * 1024 + 256 + t];
    pb[t + 512] = pbar[b * 1024 + 512 + t];
    pb[t + 768] = pbar[b * 1024 + 768 + t];
    __syncthreads();
    float x0 = 0.f, x1 = 0.f;
    {
        const float4* w4 = (const float4*)(Wv + (size_t)t * 512);
        for (int k4 = 0; k4 < 128; ++k4) {
            float4 w = w4[k4];
            x0 += w.x * pb[k4 * 4 + 0] + w.y * pb[k4 * 4 + 1]
                + w.z * pb[k4 * 4 + 2] + w.w * pb[k4 * 4 + 3];
        }
        x0 += bv[t];
    }
    {
        const float4* w4 = (const float4*)(Wv + (size_t)(t + 256) * 512);
        for (int k4 = 0; k4 < 128; ++k4) {
            float4 w = w4[k4];
            x1 += w.x * pb[512 + k4 * 4 + 0] + w.y * pb[512 + k4 * 4 + 1]
                + w.z * pb[512 + k4 * 4 + 2] + w.w * pb[512 + k4 * 4 + 3];
        }
        x1 += bv[t + 256];
    }
    const int c0 = t, c1 = t + 256;
    const float s0 = g1[c0] / sqrtf(v1[c0] + 1e-5f);
    const float s1 = g1[c1] / sqrtf(v1[c1] + 1e-5f);
    xga[b * 512 + c0] = cap[base + c0] + (x0 - m1[c0]) * s0 + b1[c0];
    xga[b * 512 + c1] = cap[base + c1] + (x1 - m1[c1]) * s1 + b1[c1];
}

// ---------------- MLP strip GEMMs (weights read once) ----------------
__global__ __launch_bounds__(256)
void mlp1(const float* __restrict__ xga, const float* __restrict__ W,
          const float* __restrict__ bias, float* __restrict__ hid)
{
    __shared__ float xs[16 * 512];
    const int r0 = blockIdx.y * 16;
    const int c0 = blockIdx.x * 64;
    for (int i = threadIdx.x; i < 2048; i += 256)
        ((float4*)xs)[i] = ((const float4*)(xga + (size_t)r0 * 512))[i];
    __syncthreads();
    const int col = c0 + (threadIdx.x & 63);
    const int rg = (threadIdx.x >> 6) * 4;
    float acc[4] = {0.f, 0.f, 0.f, 0.f};
    const float4* w4 = (const float4*)(W + (size_t)col * 512);
    for (int k4 = 0; k4 < 128; ++k4) {
        float4 w = w4[k4];
#pragma unroll
        for (int rr = 0; rr < 4; ++rr) {
            float4 x = *(const float4*)&xs[(rg + rr) * 512 + k4 * 4];
            acc[rr] += w.x * x.x + w.y * x.y + w.z * x.z + w.w * x.w;
        }
    }
    const float bb = bias[col];
#pragma unroll
    for (int rr = 0; rr < 4; ++rr)
        hid[(size_t)(r0 + rg + rr) * 1024 + col] = fmaxf(acc[rr] + bb, 0.f);
}

__global__ __launch_bounds__(256)
void mlp2(const float* __restrict__ hid, const float* __restrict__ W,
          const float* __restrict__ bias, const float* __restrict__ xga,
          float* __restrict__ tex)
{
    __shared__ float xs[16 * 1024];
    const int r0 = blockIdx.y * 16;
    const int c0 = blockIdx.x * 64;
    for (int i = threadIdx.x; i < 4096; i += 256)
        ((float4*)xs)[i] = ((const float4*)(hid + (size_t)r0 * 1024))[i];
    __syncthreads();
    const int col = c0 + (threadIdx.x & 63);
    const int rg = (threadIdx.x >> 6) * 4;
    float acc[4] = {0.f, 0.f, 0.f, 0.f};
    const float4* w4 = (const float4*)(W + (size_t)col * 1024);
    for (int k4 = 0; k4 < 256; ++k4) {
        float4 w = w4[k4];
#pragma unroll
        for (int rr = 0; rr < 4; ++rr) {
            float4 x = *(const float4*)&xs[(rg + rr) * 1024 + k4 * 4];
            acc[rr] += w.x * x.x + w.y * x.y + w.z * x.z + w.w * x.w;
        }
    }
    const float bb = bias[col];
#pragma unroll
    for (int rr = 0; rr < 4; ++rr) {
        const int row = r0 + rg + rr;
        tex[(size_t)row * 512 + col] = acc[rr] + bb + xga[(size_t)row * 512 + col];
    }
}

__global__ __launch_bounds__(256)
void norm_out(const float* __restrict__ tex, float* __restrict__ out)
{
    __shared__ float red[256];
    const int b = blockIdx.x;
    const int t = threadIdx.x;
    const float a = tex[b * 512 + t];
    const float c = tex[b * 512 + 256 + t];
    red[t] = a * a + c * c;
    __syncthreads();
    for (int s = 128; s > 0; s >>= 1) {
        if (t < s) red[t] += red[t + s];
        __syncthreads();
    }
    const float inv = 1.f / (sqrtf(red[0]) + 1e-8f);
    out[b * 512 + t] = a * inv;
    out[b * 512 + 256 + t] = c * inv;
}

extern "C" void kernel_launch(void* const* d_in, const int* in_sizes, int n_in,
                              void* d_out, int out_size, void* d_ws, size_t ws_size,
                              hipStream_t stream)
{
    const float* cap = (const float*)d_in[0];
    const int* lengths = (const int*)d_in[1];
    const float* Wq  = (const float*)d_in[2];
    const float* Wk  = (const float*)d_in[3];
    const float* Wv  = (const float*)d_in[4];
    const float* bq  = (const float*)d_in[5];
    const float* bk  = (const float*)d_in[6];
    const float* bv  = (const float*)d_in[7];
    const float* Wfq = (const float*)d_in[8];
    const float* bfq = (const float*)d_in[9];
    const float* Wfk = (const float*)d_in[10];
    const float* bfk = (const float*)d_in[11];
    const float* Wfg = (const float*)d_in[12];
    const float* bfg = (const float*)d_in[13];
    const float* g1  = (const float*)d_in[14];
    const float* b1  = (const float*)d_in[15];
    const float* m1  = (const float*)d_in[16];
    const float* v1  = (const float*)d_in[17];
    const float* Wm1 = (const float*)d_in[30];
    const float* bm1 = (const float*)d_in[31];
    const float* Wm2 = (const float*)d_in[32];
    const float* bm2 = (const float*)d_in[33];
    float* out = (float*)d_out;

    char* w = (char*)d_ws;
    const size_t MB = 1024 * 1024;
    short* capHi = (short*)(w);                // 32MB  -> Ghi after FkG gemm
    short* capLo = (short*)(w + 32 * MB);      // 32MB  -> Glo
    short* KAhi  = (short*)(w + 64 * MB);      // 64MB  [32768,1024]: cols 0-511 K, 512-1023 A=Fq(Q)
    short* KAlo  = (short*)(w + 128 * MB);     // 64MB
    char* wp = w + 192 * MB;
    short* WBhi  = (short*)wp; wp += 1048576;  // [1024,512]: rows 0-511 Wk, 512-1023 Wa
    short* WBlo  = (short*)wp; wp += 1048576;
    short* WfkHi = (short*)wp; wp += 131072;
    short* WfkLo = (short*)wp; wp += 131072;
    short* Wfg2Hi = (short*)wp; wp += 131072;
    short* Wfg2Lo = (short*)wp; wp += 131072;
    float* ba     = (float*)wp; wp += 2048;
    float* qg     = (float*)wp; wp += 262144;
    float* scorep = (float*)wp; wp += 524288;   // [128][2][256][2]
    float* pn     = (float*)wp; wp += 262144;   // [128][2][256]
    float* pbar   = (float*)wp; wp += 524288;   // [128][2][512]
    float* xga    = (float*)wp; wp += 262144;
    float* hid    = (float*)wp; wp += 524288;
    float* tex    = (float*)wp; wp += 262144;
    short* Ghi = capHi;
    short* Glo = capLo;

    // 1. splits: cap, Wk (-> WB rows 0-511), Wfk, Wfg2
    SplitArgs sa;
    sa.src[0] = cap;          sa.hi[0] = capHi;  sa.lo[0] = capLo;  sa.n4[0] = 4194304;
    sa.src[1] = Wk;           sa.hi[1] = WBhi;   sa.lo[1] = WBlo;   sa.n4[1] = 65536;
    sa.src[2] = Wfk;          sa.hi[2] = WfkHi;  sa.lo[2] = WfkLo;  sa.n4[2] = 16384;
    sa.src[3] = Wfg + 65536;  sa.hi[3] = Wfg2Hi; sa.lo[3] = Wfg2Lo; sa.n4[3] = 16384;
    split_multi<<<dim3(4096, 4), 256, 0, stream>>>(sa);

    // 2. composed Wa -> WB rows 512-1023, ba
    compose<<<dim3(512), 256, 0, stream>>>(Wq, bq, Wfq, bfq, WBhi, WBlo, ba);

    // 3. KA fused: 256^2-tile ring kernel
    gemm_ka256<<<dim3(4, 128), 512, 0, stream>>>(capHi, capLo, WBhi, WBlo, bk, ba, KAhi, KAlo);

    // 4. G = (K_h Wfk^T + bfk) * A  -> overwrites cap splits
    gemm_mfma<3><<<dim3(2, 256, 2), 256, 0, stream>>>(
        KAhi, KAlo, 1024, 256, WfkHi, WfkLo, 256, bfk,
        KAhi + 512, KAlo + 512, 1024, 256, nullptr, nullptr,
        Ghi, Glo, 512, 256, 256);

    // 5. qg at gathered rows (Q fp32 from cap)
    qg_kernel<<<dim3(256), 256, 0, stream>>>(cap, Ghi, Glo, Wq, bq, Wfg, bfg, lengths, qg);

    // 6. kg gemm with fused score partials (kg never materialized)
    gemm_mfma<4><<<dim3(2, 256, 2), 256, 0, stream>>>(
        Ghi, Glo, 512, 256, Wfg2Hi, Wfg2Lo, 256, bfg + 256,
        KAhi, KAlo, 1024, 256, qg, scorep,
        nullptr, nullptr, 0, 0, 256);

    // 7-9. softmax, parallel pbar, BN/residual
    softmax_p<<<dim3(128), 256, 0, stream>>>(scorep, pn);
    pbar_kernel<<<dim3(8, 128), 256, 0, stream>>>(pn, cap, pbar);
    bnx_kernel<<<dim3(128), 256, 0, stream>>>(pbar, cap, lengths, Wv, bv, g1, b1, m1, v1, xga);

    // 10-12. MLP, norm
    mlp1<<<dim3(16, 8), 256, 0, stream>>>(xga, Wm1, bm1, hid);
    mlp2<<<dim3(8, 8), 256, 0, stream>>>(hid, Wm2, bm2, xga, tex);
    norm_out<<<dim3(128), 256, 0, stream>>>(tex, out);
}